// Round 9
// baseline (4675.426 us; speedup 1.0000x reference)
//
#include <hip/hip_runtime.h>
#include <hip/hip_cooperative_groups.h>
#include <math.h>

namespace cg = cooperative_groups;

// Problem: SEQ_LEN=512, BATCH=64, INPUT=256, HIDDEN=512. fp32 in/out.
// v9 "short-path": v1's proven skeleton (64 blk x 8 waves, wave0 single-line
// flag poll, packed-pair publish) with the post-h critical path shortened:
//  - h fragments loaded DIRECTLY from hbuf into MFMA operands (no LDS trip)
//  - x-part MFMA hoisted before the poll (only h-MFMAs after release)
//  - lgkm-only staging barrier; pre-flag drain covers publish stores only;
//    out stores issue after the flag.
#define TT 512
#define BB 64
#define II 256
#define HH 512

#define NTHREADS 512        // 8 waves
#define NGRP 4              // batch groups (16 rows each)
#define NCT  16             // h-tile blocks per group (32 h-units each)
#define NBLOCKS (NGRP*NCT)  // 64 blocks total

#define XPAD 264            // f16 per x-row (256 + 8 pad; 528B stride, bank-staggered)

typedef _Float16 f16x8 __attribute__((ext_vector_type(8)));
typedef _Float16 f16x4 __attribute__((ext_vector_type(4)));
typedef float    f32x4 __attribute__((ext_vector_type(4)));

__device__ __forceinline__ float sig_(float v)  { return 1.0f / (1.0f + __expf(-v)); }
__device__ __forceinline__ float tanh_(float v) { float e = __expf(2.0f * v); return 1.0f - 2.0f / (e + 1.0f); }

// Barrier draining ONLY lgkmcnt (LDS). Global stores/loads stay in flight.
__device__ __forceinline__ void barrier_lds() {
    __builtin_amdgcn_sched_barrier(0);
    asm volatile("s_waitcnt lgkmcnt(0)" ::: "memory");
    __builtin_amdgcn_s_barrier();
    __builtin_amdgcn_sched_barrier(0);
}
// Raw rendezvous barrier (poll release), no counter drain.
__device__ __forceinline__ void barrier_raw() {
    __builtin_amdgcn_sched_barrier(0);
    asm volatile("" ::: "memory");
    __builtin_amdgcn_s_barrier();
    asm volatile("" ::: "memory");
    __builtin_amdgcn_sched_barrier(0);
}

__global__ void __launch_bounds__(NTHREADS, 1)
lstm_short(const float* __restrict__ x,
           const float* __restrict__ Wx,
           const float* __restrict__ bx,
           const float* __restrict__ Wh,
           const float* __restrict__ bh,
           float* __restrict__ out,
           unsigned int* __restrict__ flags,   // [NGRP][64] u32 (one 64B line/group)
           unsigned int* __restrict__ hbuf)    // [2][BB][256] u32 = packed f16 pairs
{
    __shared__ __align__(16) _Float16 AL[16 * XPAD];     // x-tile only, 8,448 B
    __shared__ __align__(16) float    exch[8 * 16 * 20]; // per-wave gate exchange

    cg::grid_group grid = cg::this_grid();

    const int blk  = blockIdx.x;
    const int grp  = blk & 3;          // batch group (16 rows)
    const int b0   = grp * 16;
    const int ct   = blk >> 2;         // 0..15, h-units [ct*32, ct*32+32)
    const int hblk = ct * 32;

    const int tid = threadIdx.x;
    const int wv  = tid >> 6;          // wave 0..7
    const int L   = tid & 63;
    const int n   = L & 15;            // MFMA A-row m / B-col n
    const int qd  = L >> 4;            // lane quad -> k = qd*8..qd*8+7

    // ---- Preload B fragments (constant across ALL 512 steps) ----
    const int g  = n & 3;
    const int hu = hblk + wv * 4 + (n >> 2);
    f16x8 bfr[24];
    #pragma unroll
    for (int kc = 0; kc < 24; ++kc) {
        int k0 = kc * 32 + qd * 8;
        const float* src = (kc < 8)
            ? (Wx + ((size_t)g * HH + hu) * II + k0)
            : (Wh + ((size_t)g * HH + hu) * HH + (k0 - 256));
        float4 u0 = ((const float4*)src)[0];
        float4 u1 = ((const float4*)src)[1];
        f16x8 b = { (_Float16)u0.x, (_Float16)u0.y, (_Float16)u0.z, (_Float16)u0.w,
                    (_Float16)u1.x, (_Float16)u1.y, (_Float16)u1.z, (_Float16)u1.w };
        bfr[kc] = b;
    }

    // Epilogue ownership: lane -> (batch be, h-unit he)
    const int be  = L >> 2;
    const int hle = L & 3;
    const int he  = hblk + wv * 4 + hle;
    float bias4[4];
    #pragma unroll
    for (int g2 = 0; g2 < 4; ++g2) bias4[g2] = bx[g2 * HH + he] + bh[g2 * HH + he];

    if (tid == 0)
        __hip_atomic_store(&flags[grp * 64 + ct], 0u,
                           __ATOMIC_RELAXED, __HIP_MEMORY_SCOPE_AGENT);
    grid.sync();

    const size_t HSEQ = (size_t)TT * BB * HH;
    float c_state = 0.0f;
    float* exchW = &exch[wv * 16 * 20];

    // This lane's h-fragment source: batch row b0+n, k-octet qd (8B qwords)
    // hbuf row = 128 qwords of packed f16 pairs.
    const unsigned long long* hrow0 =
        (const unsigned long long*)hbuf + (size_t)(b0 + n) * 128 + qd * 2;

    for (int t = 0; t < TT; ++t) {
        // ---- Stage x_t to LDS (2 float4 chunks/thread) ----
        #pragma unroll
        for (int i = 0; i < 2; ++i) {
            int ch = tid + i * NTHREADS;           // 0..1023
            int row = ch >> 6, pos = ch & 63;
            float4 v = ((const float4*)(x + ((size_t)t * BB + b0 + row) * II))[pos];
            f16x4 p = { (_Float16)v.x, (_Float16)v.y, (_Float16)v.z, (_Float16)v.w };
            *(f16x4*)&AL[row * XPAD + pos * 4] = p;
        }
        barrier_lds();   // x visible to all waves (no vmcnt drain)

        // ---- x-part MFMA NOW (off the post-h critical path), 4 chains ----
        const char* Ax = (const char*)AL + n * (XPAD * 2) + qd * 16;
        f32x4 c0 = {0,0,0,0}, c1 = {0,0,0,0}, c2 = {0,0,0,0}, c3 = {0,0,0,0};
        #pragma unroll
        for (int kc = 0; kc < 8; ++kc) {
            f16x8 a = *(const f16x8*)(Ax + kc * 64);
            if      ((kc & 3) == 0) c0 = __builtin_amdgcn_mfma_f32_16x16x32_f16(a, bfr[kc], c0, 0, 0, 0);
            else if ((kc & 3) == 1) c1 = __builtin_amdgcn_mfma_f32_16x16x32_f16(a, bfr[kc], c1, 0, 0, 0);
            else if ((kc & 3) == 2) c2 = __builtin_amdgcn_mfma_f32_16x16x32_f16(a, bfr[kc], c2, 0, 0, 0);
            else                    c3 = __builtin_amdgcn_mfma_f32_16x16x32_f16(a, bfr[kc], c3, 0, 0, 0);
        }

        // ---- Wave 0 polls the group's flag line; barrier releases ----
        if (t > 0 && wv == 0) {
            const unsigned int* fp = flags + grp * 64;
            for (;;) {
                unsigned f = (L < NCT)
                    ? __hip_atomic_load(&fp[L], __ATOMIC_RELAXED, __HIP_MEMORY_SCOPE_AGENT)
                    : 0xFFFFFFFFu;
                if (__all((int)(f >= (unsigned)t))) break;
                __builtin_amdgcn_s_sleep(1);
            }
        }
        barrier_raw();

        // ---- h-part: DIRECT per-lane fragment loads from hbuf -> MFMA ----
        if (t > 0) {
            const unsigned long long* hb = hrow0 + (size_t)(t & 1) * (BB * 128);
            unsigned long long hq[16][2];
            #pragma unroll
            for (int kc = 0; kc < 16; ++kc) {      // independent, all in flight
                hq[kc][0] = __hip_atomic_load(hb + kc * 8 + 0,
                                              __ATOMIC_RELAXED, __HIP_MEMORY_SCOPE_AGENT);
                hq[kc][1] = __hip_atomic_load(hb + kc * 8 + 1,
                                              __ATOMIC_RELAXED, __HIP_MEMORY_SCOPE_AGENT);
            }
            #pragma unroll
            for (int kc = 0; kc < 16; ++kc) {
                union { unsigned long long q[2]; f16x8 v; } cvt;
                cvt.q[0] = hq[kc][0]; cvt.q[1] = hq[kc][1];
                f16x8 a = cvt.v;
                if      ((kc & 3) == 0) c0 = __builtin_amdgcn_mfma_f32_16x16x32_f16(a, bfr[kc + 8], c0, 0, 0, 0);
                else if ((kc & 3) == 1) c1 = __builtin_amdgcn_mfma_f32_16x16x32_f16(a, bfr[kc + 8], c1, 0, 0, 0);
                else if ((kc & 3) == 2) c2 = __builtin_amdgcn_mfma_f32_16x16x32_f16(a, bfr[kc + 8], c2, 0, 0, 0);
                else                    c3 = __builtin_amdgcn_mfma_f32_16x16x32_f16(a, bfr[kc + 8], c3, 0, 0, 0);
            }
        }
        f32x4 acc = (c0 + c1) + (c2 + c3);

        // ---- Intra-wave exchange: C[row=qd*4+r][col=n] -> gates per (b,h) ----
        #pragma unroll
        for (int r = 0; r < 4; ++r)
            exchW[(qd * 4 + r) * 20 + n] = acc[r];
        float4 pre4 = *(const float4*)&exchW[be * 20 + hle * 4];

        // ---- Gates; c_state in-register ----
        float pf = pre4.x + bias4[0];
        float pi = pre4.y + bias4[1];
        float po = pre4.z + bias4[2];
        float pc = pre4.w + bias4[3];
        float fg = sig_(pf), ig = sig_(pi), og = sig_(po);
        float cn = fg * c_state + ig * tanh_(pc);
        float hv = og * tanh_(cn);
        c_state = cn;

        // ---- Publish h_t as packed f16 pairs ----
        {
            union { _Float16 f; unsigned short u; } cv; cv.f = (_Float16)hv;
            unsigned mine  = cv.u;
            unsigned other = (unsigned)__shfl_xor((int)mine, 1, 64);
            if ((hle & 1) == 0) {
                unsigned pk = mine | (other << 16);
                unsigned int* hdst = hbuf + (size_t)((t + 1) & 1) * (BB * 256);
                __hip_atomic_store(&hdst[(unsigned)(b0 + be) * 256 + (unsigned)(he >> 1)],
                                   pk, __ATOMIC_RELAXED, __HIP_MEMORY_SCOPE_AGENT);
            }
        }

        // ---- Drain = publish stores only (h loads consumed; out issues after
        // the flag and acks during the next step's slack) ----
        __builtin_amdgcn_sched_barrier(0);
        asm volatile("s_waitcnt vmcnt(0) lgkmcnt(0)" ::: "memory");
        __builtin_amdgcn_s_barrier();
        __builtin_amdgcn_sched_barrier(0);
        if (t != TT - 1 && tid == 0)
            __hip_atomic_store(&flags[grp * 64 + ct], (unsigned)(t + 1),
                               __ATOMIC_RELAXED, __HIP_MEMORY_SCOPE_AGENT);

        out[((size_t)t * BB + b0 + be) * HH + he] = hv;
        if (t == TT - 1) {
            size_t r = (size_t)(b0 + be) * HH + he;
            out[HSEQ + r] = hv;                        // h_last
            out[HSEQ + (size_t)BB * HH + r] = cn;      // c_last
        }
        // hbuf WAR safety (unchanged from v1): a block reaches step t+1's
        // publishes only after all blocks flagged t (their step-t reads of
        // hbuf[(t+1)&1]... completed before their own flag t).
    }
}

extern "C" void kernel_launch(void* const* d_in, const int* in_sizes, int n_in,
                              void* d_out, int out_size, void* d_ws, size_t ws_size,
                              hipStream_t stream)
{
    const float* x  = (const float*)d_in[0];
    const float* Wx = (const float*)d_in[1];
    const float* bx = (const float*)d_in[2];
    const float* Wh = (const float*)d_in[3];
    const float* bh = (const float*)d_in[4];
    float* out = (float*)d_out;

    // ws: [0,4KB) epoch flags; [4KB, 4KB+128KB) h f16-pair ping-pong
    unsigned int* flags = (unsigned int*)d_ws;
    unsigned int* hbuf  = (unsigned int*)((char*)d_ws + 4096);

    void* args[] = { (void*)&x, (void*)&Wx, (void*)&bx, (void*)&Wh, (void*)&bh,
                     (void*)&out, (void*)&flags, (void*)&hbuf };
    hipLaunchCooperativeKernel((const void*)lstm_short,
                               dim3(NBLOCKS), dim3(NTHREADS),
                               args, 0, stream);
}